// Round 8
// baseline (217.452 us; speedup 1.0000x reference)
//
#include <hip/hip_runtime.h>

// n=2048 rows, f=32 features. Output row r = [emb[i] (32) | emb[j] (32) | sw[j]],
// i = r>>11, j = r&2047. Output = 2048*2048*65 floats = 1.09 GB, write-BW bound.
//
// v6: register read-ahead — store operands leave LDS one slab EARLY.
// Evidence chain: v2b (no barrier), v3 (pipelined), v4 (load-free), v5 (no
// nt) all cluster at 5.1-5.35 TB/s vs fillBuffer's 6.5. The one shared trait
// left: every store burst is fronted by an s_waitcnt lgkmcnt for ds_reads
// issued immediately before it -> ~120 cyc holes in the store stream, phase-
// locked across waves. Here each STEP captures slab s+1 into VGPR banks
// (RA/RB, 5xf32x4 each) right after scattering it, a full iteration before
// it is stored; the lgkm wait at store time refers to reads ~20 instructions
// old. Stores themselves read registers only.
//
// Side effect: drain no longer reads LDS, so ONE 4160 B buffer per wave
// suffices (per-wave in-order DS pipe: scatter(s+1) cannot pass read(s)
// issued earlier in program order — semantics hardware-verified by v4).
// LDS/block: 16,640 B. a-part (emb[i], wave-uniform) written once.
//
// Per STEP(s): scatter(s+1)->buf; ds_read buf->RN; store(s) from RC;
// prefetch globals(s+2). Fully unrolled, explicit register banks (no
// runtime-indexed register arrays).

#define NROWS 2048u
#define BLOCK_ROWS 512u                 // per block (4 waves x 128 rows)
#define WAVE_ROWS 128u                  // per wave
#define SLAB_ROWS 16u
#define NSLABS 8u                       // 128/16
#define SLAB_FLOATS (SLAB_ROWS * 65u)   // 1040 floats = 4160 B
#define SLAB_F4 (SLAB_FLOATS / 4u)      // 260 float4, exact

typedef float f32x4 __attribute__((ext_vector_type(4)));

__global__ __launch_bounds__(256) void expand_rra(
    const float* __restrict__ emb,   // [2048*32]
    const float* __restrict__ sw,    // [2048]
    f32x4* __restrict__ out)         // flat output as float4
{
    __shared__ __align__(16) float lds[4][SLAB_FLOATS];   // 16,640 B

    const unsigned tid  = threadIdx.x;
    const unsigned wave = tid >> 6;
    const unsigned lane = tid & 63u;

    const unsigned r0 = blockIdx.x * BLOCK_ROWS + wave * WAVE_ROWS;
    const unsigned i  = r0 >> 11;             // constant per wave
    const unsigned j0 = r0 & (NROWS - 1u);    // j0..j0+127, no wrap

    float* W = &lds[wave][0];
    const f32x4* L4 = (const f32x4*)W;

    // ---- a-part: emb[i] wave-uniform, written ONCE (scatter never touches
    //      cols 0..31 again). Lanes 0-31 rows 0-7, lanes 32-63 rows 8-15.
    const float vi = emb[i * 32u + (lane & 31u)];
    const unsigned rbase = (lane >> 5) * 8u;
#pragma unroll
    for (unsigned rp = 0; rp < 8u; ++rp)
        W[(rbase + rp) * 65u + (lane & 31u)] = vi;

    // b-scatter geometry: global f4 g of a slab -> float addr
    // (g>>3)*65 + 32 + (g&7)*4; g=lane and g=lane+64 (addr d0+520).
    const unsigned d0 = (lane >> 3) * 65u + 32u + (lane & 7u) * 4u;

    f32x4 RA0, RA1, RA2, RA3, RA4;   // store-operand bank A (slab even)
    f32x4 RB0, RB1, RB2, RB3, RB4;   // bank B (slab odd)
    f32x4 pA0, pA1, pB0, pB1;        // global-prefetch banks
    float psA, psB;

    // ---- prologue: slab0 -> buffer -> RA;  slab1 globals -> B bank.
    {
        const f32x4* ej = (const f32x4*)(emb + (size_t)j0 * 32u);
        const f32x4 a0 = ej[lane];
        const f32x4 a1 = ej[lane + 64u];
        const float s0 = sw[j0 + (lane & 15u)];
        W[d0 + 0u] = a0.x; W[d0 + 1u] = a0.y;
        W[d0 + 2u] = a0.z; W[d0 + 3u] = a0.w;
        W[d0 + 520u] = a1.x; W[d0 + 521u] = a1.y;
        W[d0 + 522u] = a1.z; W[d0 + 523u] = a1.w;
        if (lane < 16u) W[lane * 65u + 64u] = s0;
    }
    {
        const f32x4* ej = (const f32x4*)(emb + (size_t)(j0 + SLAB_ROWS) * 32u);
        pB0 = ej[lane];
        pB1 = ej[lane + 64u];
        psB = sw[j0 + SLAB_ROWS + (lane & 15u)];
    }
    RA0 = L4[lane];         RA1 = L4[64u + lane];
    RA2 = L4[128u + lane];  RA3 = L4[192u + lane];
    RA4 = L4[256u + (lane & 3u)];

    const unsigned base0 = (r0 >> 4) * SLAB_F4;

    // STEP(s): scatter slab s+1 (from PC bank) into the single buffer,
    // read it back into RN bank, store slab s from RC bank (regs only),
    // prefetch slab s+2 globals into PN bank.
#define STEP(S, RC0, RC1, RC2, RC3, RC4, RN0, RN1, RN2, RN3, RN4,          \
             PC0, PC1, PSC, PN0, PN1, PSN)                                 \
    {                                                                      \
        if ((S) + 1u < NSLABS) {                                           \
            W[d0 + 0u] = PC0.x; W[d0 + 1u] = PC0.y;                        \
            W[d0 + 2u] = PC0.z; W[d0 + 3u] = PC0.w;                        \
            W[d0 + 520u] = PC1.x; W[d0 + 521u] = PC1.y;                    \
            W[d0 + 522u] = PC1.z; W[d0 + 523u] = PC1.w;                    \
            if (lane < 16u) W[lane * 65u + 64u] = PSC;                     \
            RN0 = L4[lane];         RN1 = L4[64u + lane];                  \
            RN2 = L4[128u + lane];  RN3 = L4[192u + lane];                 \
            RN4 = L4[256u + (lane & 3u)];                                  \
        }                                                                  \
        {                                                                  \
            const unsigned ob = base0 + (S) * SLAB_F4;                     \
            out[ob + lane]        = RC0;                                   \
            out[ob + 64u + lane]  = RC1;                                   \
            out[ob + 128u + lane] = RC2;                                   \
            out[ob + 192u + lane] = RC3;                                   \
            if (lane < 4u) out[ob + 256u + lane] = RC4;                    \
        }                                                                  \
        if ((S) + 2u < NSLABS) {                                           \
            const f32x4* ej = (const f32x4*)                               \
                (emb + (size_t)(j0 + ((S) + 2u) * SLAB_ROWS) * 32u);       \
            PN0 = ej[lane];                                                \
            PN1 = ej[lane + 64u];                                          \
            PSN = sw[j0 + ((S) + 2u) * SLAB_ROWS + (lane & 15u)];          \
        }                                                                  \
    }

    STEP(0u, RA0,RA1,RA2,RA3,RA4, RB0,RB1,RB2,RB3,RB4, pB0,pB1,psB, pA0,pA1,psA)
    STEP(1u, RB0,RB1,RB2,RB3,RB4, RA0,RA1,RA2,RA3,RA4, pA0,pA1,psA, pB0,pB1,psB)
    STEP(2u, RA0,RA1,RA2,RA3,RA4, RB0,RB1,RB2,RB3,RB4, pB0,pB1,psB, pA0,pA1,psA)
    STEP(3u, RB0,RB1,RB2,RB3,RB4, RA0,RA1,RA2,RA3,RA4, pA0,pA1,psA, pB0,pB1,psB)
    STEP(4u, RA0,RA1,RA2,RA3,RA4, RB0,RB1,RB2,RB3,RB4, pB0,pB1,psB, pA0,pA1,psA)
    STEP(5u, RB0,RB1,RB2,RB3,RB4, RA0,RA1,RA2,RA3,RA4, pA0,pA1,psA, pB0,pB1,psB)
    STEP(6u, RA0,RA1,RA2,RA3,RA4, RB0,RB1,RB2,RB3,RB4, pB0,pB1,psB, pA0,pA1,psA)
    STEP(7u, RB0,RB1,RB2,RB3,RB4, RA0,RA1,RA2,RA3,RA4, pA0,pA1,psA, pB0,pB1,psB)
#undef STEP
}

extern "C" void kernel_launch(void* const* d_in, const int* in_sizes, int n_in,
                              void* d_out, int out_size, void* d_ws, size_t ws_size,
                              hipStream_t stream) {
    const float* emb = (const float*)d_in[0];   // [2048, 32] f32
    const float* sw  = (const float*)d_in[1];   // [2048] f32
    f32x4* out       = (f32x4*)d_out;

    const unsigned blocks = (NROWS * NROWS) / BLOCK_ROWS;   // 8192
    expand_rra<<<dim3(blocks), dim3(256), 0, stream>>>(emb, sw, out);
}

// Round 9
// 202.152 us; speedup vs baseline: 1.0757x; 1.0757x over previous
//
#include <hip/hip_runtime.h>

// n=2048 rows, f=32 features. Output row r = [emb[i] (32) | emb[j] (32) | sw[j]],
// i = r>>11, j = r&2047. Output = 2048*2048*65 floats = 1.09 GB, write-BW bound.
//
// v7: v5 (pipelined, double-buffered, plain stores) with ONE change:
// dynamic LDS padded to 61,440 B/block -> 2 blocks/CU -> 8 waves/CU.
// Evidence: every intra-wave schedule variant (v2b/v3/v4/v5/v6) sits at
// 5.0-5.35 TB/s; the only mild trend is occupancy (32 waves/CU: 213 us,
// 16 waves/CU: 204 us). fillBufferAligned does 6.5 TB/s at ~3.5 waves/CU --
// few waves, large contiguous chunks. Theory: effective HBM write BW is
// limited by the number of concurrent write streams (DRAM row-buffer
// locality), one stream per resident wave. 8 waves/CU ~= 2K streams, near
// fillBuffer's regime. Required per-wave rate at ceiling: 1 KB store per
// ~775 cycles -- trivially sustainable with 2 waves/SIMD.

#define NROWS 2048u
#define BLOCK_ROWS 512u                 // per block (4 waves x 128 rows)
#define WAVE_ROWS 128u                  // per wave
#define SLAB_ROWS 16u
#define NSLABS 8u                       // 128/16
#define SLAB_FLOATS (SLAB_ROWS * 65u)   // 1040 floats = 4160 B
#define SLAB_F4 (SLAB_FLOATS / 4u)      // 260 float4, exact
#define LDS_BYTES 61440u                // pad -> 2 blocks/CU (160 KiB / CU)

typedef float f32x4 __attribute__((ext_vector_type(4)));

__global__ __launch_bounds__(256) void expand_pipe(
    const float* __restrict__ emb,   // [2048*32]
    const float* __restrict__ sw,    // [2048]
    f32x4* __restrict__ out)         // flat output as float4
{
    extern __shared__ __align__(16) float dynlds[];   // 61,440 B requested

    const unsigned tid  = threadIdx.x;
    const unsigned wave = tid >> 6;
    const unsigned lane = tid & 63u;

    // Wave's first output row. 128-aligned, 128 | 2048 -> i constant for the
    // whole wave, j-range j0..j0+127 contiguous (never wraps).
    const unsigned r0 = blockIdx.x * BLOCK_ROWS + wave * WAVE_ROWS;
    const unsigned i  = r0 >> 11;
    const unsigned j0 = r0 & (NROWS - 1u);

    // wave's two buffers, back to back.
    float* buf0 = dynlds + (wave * 2u + 0u) * SLAB_FLOATS;
    float* buf1 = dynlds + (wave * 2u + 1u) * SLAB_FLOATS;

    // ---- prologue: a-part. emb[i] is constant for all 128 rows: write cols
    // 0..31 of all 16 slab-rows into BOTH buffers once. Lanes 0-31 rows 0-7,
    // lanes 32-63 rows 8-15, col = lane&31.
    const float vi = emb[i * 32u + (lane & 31u)];
    const unsigned rbase = (lane >> 5) * 8u;
#pragma unroll
    for (unsigned rp = 0; rp < 8u; ++rp) {
        buf0[(rbase + rp) * 65u + (lane & 31u)] = vi;
        buf1[(rbase + rp) * 65u + (lane & 31u)] = vi;
    }

    // Static scatter destination for the b-part: global f4 index g in the
    // 128-f4 slab maps to LDS float addr (g>>3)*65 + 32 + (g&7)*4.
    // For g = lane+64 the addr is just d0 + 8*65.
    const unsigned d0 = (lane >> 3) * 65u + 32u + (lane & 7u) * 4u;

    // ---- prologue: prefetch + scatter slab 0 into buffer 0.
    {
        const f32x4* ej = (const f32x4*)(emb + (size_t)j0 * 32u);
        const f32x4 pa = ej[lane];
        const f32x4 pb = ej[lane + 64u];
        const float ps = sw[j0 + (lane & 15u)];
        buf0[d0 + 0u] = pa.x; buf0[d0 + 1u] = pa.y;
        buf0[d0 + 2u] = pa.z; buf0[d0 + 3u] = pa.w;
        buf0[d0 + 520u + 0u] = pb.x; buf0[d0 + 520u + 1u] = pb.y;
        buf0[d0 + 520u + 2u] = pb.z; buf0[d0 + 520u + 3u] = pb.w;
        if (lane < 16u) buf0[lane * 65u + 64u] = ps;
    }

    // ---- pipelined main loop over 8 slabs (fully unrolled, static buffers).
#pragma unroll
    for (unsigned s = 0; s < NSLABS; ++s) {
        float* CUR = (s & 1u) ? buf1 : buf0;
        float* NXT = (s & 1u) ? buf0 : buf1;

        // prefetch slab s+1 -> registers (independent of the drain below;
        // scheduler hoists the loads so latency hides under the stores)
        f32x4 pa, pb;
        float ps = 0.0f;
        if (s + 1u < NSLABS) {
            const f32x4* ej =
                (const f32x4*)(emb + (size_t)(j0 + (s + 1u) * SLAB_ROWS) * 32u);
            pa = ej[lane];
            pb = ej[lane + 64u];
            ps = sw[j0 + (s + 1u) * SLAB_ROWS + (lane & 15u)];
        }

        // drain buffer CUR (slab s): 260 float4, unit stride, plain stores.
        const f32x4* L4 = (const f32x4*)CUR;
        const unsigned obase = ((r0 + s * SLAB_ROWS) >> 4) * SLAB_F4;
#pragma unroll
        for (unsigned p = 0; p < 4u; ++p)
            out[obase + p * 64u + lane] = L4[p * 64u + lane];
        if (lane < 4u)
            out[obase + 256u + lane] = L4[256u + lane];

        // scatter prefetched slab s+1 into the other buffer.
        if (s + 1u < NSLABS) {
            NXT[d0 + 0u] = pa.x; NXT[d0 + 1u] = pa.y;
            NXT[d0 + 2u] = pa.z; NXT[d0 + 3u] = pa.w;
            NXT[d0 + 520u + 0u] = pb.x; NXT[d0 + 520u + 1u] = pb.y;
            NXT[d0 + 520u + 2u] = pb.z; NXT[d0 + 520u + 3u] = pb.w;
            if (lane < 16u) NXT[lane * 65u + 64u] = ps;
        }
    }
}

extern "C" void kernel_launch(void* const* d_in, const int* in_sizes, int n_in,
                              void* d_out, int out_size, void* d_ws, size_t ws_size,
                              hipStream_t stream) {
    const float* emb = (const float*)d_in[0];   // [2048, 32] f32
    const float* sw  = (const float*)d_in[1];   // [2048] f32
    f32x4* out       = (f32x4*)d_out;

    const unsigned blocks = (NROWS * NROWS) / BLOCK_ROWS;   // 8192
    expand_pipe<<<dim3(blocks), dim3(256), LDS_BYTES, stream>>>(emb, sw, out);
}